// Round 6
// baseline (138.772 us; speedup 1.0000x reference)
//
#include <hip/hip_runtime.h>
#include <cstdint>
#include <cstddef>
#include <math.h>

// B=2, L=2048, E=1024, H=16, D=64
#define BB 2
#define LL 2048
#define EE 1024
#define HH 16
#define DD 64
#define MM (BB*LL)

typedef short short8 __attribute__((ext_vector_type(8)));
typedef float f32x4 __attribute__((ext_vector_type(4)));
typedef float f32x16 __attribute__((ext_vector_type(16)));

#define GPTR __attribute__((address_space(1)))
#define LPTR __attribute__((address_space(3)))

__device__ __forceinline__ unsigned short f32_bf16(float f) {
  union { float f; unsigned u; } c; c.f = f;
  c.u += 0x7fffu + ((c.u >> 16) & 1u);
  return (unsigned short)(c.u >> 16);
}

__device__ __forceinline__ unsigned pk_bf16(float lo, float hi) {
  unsigned r;
  asm("v_cvt_pk_bf16_f32 %0, %1, %2" : "=v"(r) : "v"(lo), "v"(hi));
  return r;
}
// v_permlane32_swap_b32 vdst, vsrc:
//   vdst_new = [vdst_old lanes 0-31 | vsrc_old lanes 0-31]
//   vsrc_new = [vdst_old lanes 32-63 | vsrc_old lanes 32-63]
// Operands must be DISTINCT live values (else regalloc may alias them).
__device__ __forceinline__ void swap32(unsigned &a, unsigned &b) {
  asm("v_permlane32_swap_b32 %0, %1" : "+v"(a), "+v"(b));
}
// cross-half (lane vs lane^32) reduce via permlane32_swap: VALU-speed, no DS op.
__device__ __forceinline__ float xh_max(float v) {
  union { float f; unsigned u; } a, b;
  a.f = v;
  asm("v_mov_b32 %0, %1" : "=&v"(b.u) : "v"(a.u));   // forced distinct copy
  asm("v_permlane32_swap_b32 %0, %1" : "+v"(a.u), "+v"(b.u));
  return fmaxf(a.f, b.f);   // a = v[l31] (low-half val), b = v[32+l31]
}
__device__ __forceinline__ float xh_sum(float v) {
  union { float f; unsigned u; } a, b;
  a.f = v;
  asm("v_mov_b32 %0, %1" : "=&v"(b.u) : "v"(a.u));
  asm("v_permlane32_swap_b32 %0, %1" : "+v"(a.u), "+v"(b.u));
  return a.f + b.f;
}
__device__ __forceinline__ f32x16 zero16() {
  f32x16 v;
  #pragma unroll
  for (int e = 0; e < 16; ++e) v[e] = 0.f;
  return v;
}

// ---------------- fp32 -> bf16 conversion (x + 4 weights fused) ----------------
__global__ void cvt_all(const float* __restrict__ x,  const float* __restrict__ wq,
                        const float* __restrict__ wk, const float* __restrict__ wv,
                        const float* __restrict__ wo,
                        unsigned short* __restrict__ xb,  unsigned short* __restrict__ wqb,
                        unsigned short* __restrict__ wkb, unsigned short* __restrict__ wvb,
                        unsigned short* __restrict__ wob)
{
  int i = (blockIdx.x * 256 + threadIdx.x) * 4;
  if (i >= MM * EE + 4 * EE * EE) return;
  const float* s; unsigned short* d; int off;
  if (i < MM * EE) { s = x; d = xb; off = i; }
  else {
    int k = i - MM * EE;
    int w = k >> 20;               // EE*EE = 1<<20
    off = k & (EE * EE - 1);
    s = (w == 0) ? wq : (w == 1) ? wk : (w == 2) ? wv : wo;
    d = (w == 0) ? wqb : (w == 1) ? wkb : (w == 2) ? wvb : wob;
  }
  float4 v = *(const float4*)(s + off);
  union { unsigned short s[4]; uint2 u; } o;
  o.s[0] = f32_bf16(v.x); o.s[1] = f32_bf16(v.y);
  o.s[2] = f32_bf16(v.z); o.s[3] = f32_bf16(v.w);
  *(uint2*)(d + off) = o.u;
}

// ---------------- 128x128 bf16 GEMM (NT: A MxK, W NxK) ----------------
// MODE 0: z=0: Q -> (B,H,L,D), *mask*(1/sqrt(D))*log2(e); z=1: K -> (B,H,L,D), *mask;
//         z=2: V^T -> (B,H,D,L), *mask.
// MODE 1: out = A @ W0^T + bias, fp32 row-major.
template<int MODE>
__global__ __launch_bounds__(256, 2)
void gemm128(const unsigned short* __restrict__ A,
             const unsigned short* __restrict__ W0,
             const unsigned short* __restrict__ W1,
             const unsigned short* __restrict__ W2,
             const float* __restrict__ mask,
             const float* __restrict__ bias,
             unsigned short* __restrict__ O0,
             unsigned short* __restrict__ O1,
             unsigned short* __restrict__ O2,
             float* __restrict__ OF)
{
  constexpr int K = EE;
  const int tid = threadIdx.x;
  const int lane = tid & 63;
  const int wid = tid >> 6;
  const int g = lane >> 4, li = lane & 15;
  const int m0 = blockIdx.y * 128;
  const int n0 = blockIdx.x * 128;
  const int z = blockIdx.z;

  const unsigned short* Wp = W0;
  if (MODE == 0) Wp = (z == 0) ? W0 : ((z == 1) ? W1 : W2);

  __shared__ unsigned short As[128 * 64];
  __shared__ unsigned short Bs[128 * 64];

  f32x4 acc[4][4];
  f32x4 zero = {0.f, 0.f, 0.f, 0.f};
  #pragma unroll
  for (int i = 0; i < 4; ++i)
    #pragma unroll
    for (int j = 0; j < 4; ++j) acc[i][j] = zero;

  const int wm = (wid >> 1) * 64;
  const int wn = (wid & 1) * 64;

  for (int kt = 0; kt < K; kt += 64) {
    #pragma unroll
    for (int j = 0; j < 4; ++j) {
      int c = j * 256 + tid;
      int row = c >> 3;
      int lcol = ((c & 7) * 16) ^ ((row & 7) << 4);
      __builtin_amdgcn_global_load_lds(
        (const GPTR void*)((const char*)(A + (size_t)(m0 + row) * K + kt) + lcol),
        (LPTR void*)((char*)As + c * 16), 16, 0, 0);
      __builtin_amdgcn_global_load_lds(
        (const GPTR void*)((const char*)(Wp + (size_t)(n0 + row) * K + kt) + lcol),
        (LPTR void*)((char*)Bs + c * 16), 16, 0, 0);
    }
    __syncthreads();

    #pragma unroll
    for (int kk = 0; kk < 2; ++kk) {
      short8 a[4], b[4];
      const int colb = (kk * 32 + g * 8) * 2;
      #pragma unroll
      for (int i = 0; i < 4; ++i) {
        int ar = wm + i * 16 + li;
        a[i] = *(const short8*)((const char*)As + ar * 128 + (colb ^ ((ar & 7) << 4)));
        int br = wn + i * 16 + li;
        b[i] = *(const short8*)((const char*)Bs + br * 128 + (colb ^ ((br & 7) << 4)));
      }
      #pragma unroll
      for (int i = 0; i < 4; ++i)
        #pragma unroll
        for (int j = 0; j < 4; ++j)
          acc[i][j] = __builtin_amdgcn_mfma_f32_16x16x32_bf16(a[i], b[j], acc[i][j], 0, 0, 0);
    }
    __syncthreads();
  }

  // epilogue. C/D layout: col = li, row = g*4 + r
  if (MODE == 0) {
    if (z == 2) {
      #pragma unroll
      for (int i = 0; i < 4; ++i) {
        int mbase = m0 + wm + i * 16 + g * 4;
        int bb2 = mbase >> 11;
        int l0  = mbase & (LL - 1);
        float mk[4];
        #pragma unroll
        for (int r = 0; r < 4; ++r) mk[r] = mask[mbase + r];
        #pragma unroll
        for (int j = 0; j < 4; ++j) {
          int n = n0 + wn + j * 16 + li;
          int h2 = n >> 6, dd2 = n & 63;
          union { unsigned short s[4]; uint2 u; } o;
          #pragma unroll
          for (int r = 0; r < 4; ++r) o.s[r] = f32_bf16(acc[i][j][r] * mk[r]);
          *(uint2*)(O2 + ((size_t)(bb2 * HH + h2) * DD + dd2) * LL + l0) = o.u;
        }
      }
    } else {
      unsigned short* Op = (z == 0) ? O0 : O1;
      // z==0: 1/sqrt(64) * log2(e) folded into Q (softmax runs in exp2 domain)
      const float sc = (z == 0) ? 0.125f * 1.44269504088896f : 1.0f;
      #pragma unroll
      for (int i = 0; i < 4; ++i) {
        #pragma unroll
        for (int r = 0; r < 4; ++r) {
          int m = m0 + wm + i * 16 + g * 4 + r;
          float mk = mask[m] * sc;
          int bb = m >> 11;
          int l  = m & (LL - 1);
          #pragma unroll
          for (int j = 0; j < 4; ++j) {
            int n = n0 + wn + j * 16 + li;
            int h = n >> 6, d = n & 63;
            size_t off = (((size_t)(bb * HH + h)) * LL + l) * DD + d;
            Op[off] = f32_bf16(acc[i][j][r] * mk);
          }
        }
      }
    }
  } else {
    #pragma unroll
    for (int i = 0; i < 4; ++i) {
      #pragma unroll
      for (int j = 0; j < 4; ++j) {
        int n = n0 + wn + j * 16 + li;
        float bv = bias[n];
        #pragma unroll
        for (int r = 0; r < 4; ++r) {
          int m = m0 + wm + i * 16 + g * 4 + r;
          OF[(size_t)m * EE + n] = acc[i][j][r] + bv;
        }
      }
    }
  }
}

// ---------------- causal flash attention: 1 wave/block, no LDS, no barriers ----
// Q (B,H,L,D) pre-scaled by mask*(1/sqrt(D))*log2e; K (B,H,L,D) *mask; VT (B,H,D,L) *mask.
// Each wave owns 32 q-rows (q = q0 + lane&31). KVBLK=32 per iteration.
// K/V^T fragments loaded DIRECTLY global->VGPR (L2-resident via XCD colocation),
// register ping-pong prefetched one tile ahead. Softmax lane-local + permlane swaps.
// S^T = mfma(K, Q): q = lane&31, kv = (reg&3)+8*(reg>>2)+4*hi
// O^T = mfma(VT, P): q = lane&31, d  = (reg&3)+8*(reg>>2)+4*hi (+32 for ot1)
__global__ __launch_bounds__(64, 2)
void attn3(const unsigned short* __restrict__ Q,
           const unsigned short* __restrict__ K,
           const unsigned short* __restrict__ VT,
           unsigned short* __restrict__ Y)
{
  const int lane = threadIdx.x;
  const int l31 = lane & 31, hi = lane >> 5;

  const int id = blockIdx.x;
  const int lo = id & 7;                    // XCD
  const int r_ = id >> 3;
  const int bh = (r_ & 3) * 8 + lo;         // 4 heads per XCD (KV 2MB <= 4MB L2)
  const int qt = 63 - (r_ >> 2);            // heavy q-tiles first
  const int q0 = qt * 32;
  const int b = bh >> 4, h = bh & (HH - 1);
  const size_t kbase = (size_t)bh * LL * DD;

  const unsigned short* Kg  = K + kbase;
  const unsigned short* VTg = VT + kbase;   // (D,L) within head

  const int qrow = q0 + l31;
  const int nt = qt + 1;                    // kv tiles of 32

  short8 qf[4];
  {
    const unsigned short* Qr = Q + kbase + (size_t)qrow * DD + hi * 8;
    #pragma unroll
    for (int kc = 0; kc < 4; ++kc) qf[kc] = *(const short8*)(Qr + kc * 16);
  }

  f32x16 ot0 = zero16(), ot1 = zero16();
  float m = -INFINITY, lsum = 0.f;

  short8 kA[4], vA[4], kB[4], vB[4];

  // prologue: load tile 0 into A buffers
  {
    const unsigned short* Kp = Kg + ((size_t)l31 << 6) + hi * 8;
    #pragma unroll
    for (int kc = 0; kc < 4; ++kc) kA[kc] = *(const short8*)(Kp + kc * 16);
    const unsigned short* Vp = VTg + ((size_t)l31 << 11) + hi * 8;
    vA[0] = *(const short8*)(Vp);
    vA[1] = *(const short8*)(Vp + 16);
    vA[2] = *(const short8*)(Vp + (32 << 11));
    vA[3] = *(const short8*)(Vp + (32 << 11) + 16);
  }

  auto body = [&](short8 (&ck)[4], short8 (&cv)[4],
                  short8 (&nk)[4], short8 (&nv)[4], int t) {
    const int kv0 = t << 5;
    // ---- prefetch next tile into the other buffers (in flight during compute) ----
    if (t + 1 < nt) {
      const unsigned short* Kp = Kg + ((size_t)(kv0 + 32 + l31) << 6) + hi * 8;
      #pragma unroll
      for (int kc = 0; kc < 4; ++kc) nk[kc] = *(const short8*)(Kp + kc * 16);
      const unsigned short* Vp = VTg + ((size_t)l31 << 11) + kv0 + 32 + hi * 8;
      nv[0] = *(const short8*)(Vp);
      nv[1] = *(const short8*)(Vp + 16);
      nv[2] = *(const short8*)(Vp + (32 << 11));
      nv[3] = *(const short8*)(Vp + (32 << 11) + 16);
    }

    // ---- S^T = K · Q^T (log2 units) ----
    f32x16 s = zero16();
    __builtin_amdgcn_s_setprio(1);
    #pragma unroll
    for (int kc = 0; kc < 4; ++kc)
      s = __builtin_amdgcn_mfma_f32_32x32x16_bf16(ck[kc], qf[kc], s, 0, 0, 0);
    __builtin_amdgcn_s_setprio(0);

    // ---- causal mask: only the diagonal tile (t == nt-1, kv0 == q0) ----
    if (t == nt - 1) {
      #pragma unroll
      for (int i = 0; i < 16; ++i) {
        int kvr = (i & 3) + 8 * (i >> 2) + 4 * hi;   // kv - kv0
        if (kvr > l31) s[i] = -INFINITY;
      }
    }

    // ---- online softmax (exp2 domain), lane-local + permlane cross-half ----
    float red[8];
    #pragma unroll
    for (int e = 0; e < 8; ++e) red[e] = fmaxf(s[e], s[e + 8]);
    #pragma unroll
    for (int st = 4; st >= 1; st >>= 1)
      #pragma unroll
      for (int e = 0; e < 4; ++e) if (e < st) red[e] = fmaxf(red[e], red[e + st]);
    float mv = xh_max(red[0]);

    if (!__all(mv <= m + 8.0f)) {            // T13 defer-max (P bounded by 2^8)
      float mnew = fmaxf(m, mv);
      float al = exp2f(m - mnew);
      m = mnew;
      lsum *= al;
      #pragma unroll
      for (int e = 0; e < 16; ++e) { ot0[e] *= al; ot1[e] *= al; }
    }

    float ra[8];
    #pragma unroll
    for (int e = 0; e < 16; ++e) s[e] = exp2f(s[e] - m);
    #pragma unroll
    for (int e = 0; e < 8; ++e) ra[e] = s[e] + s[e + 8];
    #pragma unroll
    for (int st = 4; st >= 1; st >>= 1)
      #pragma unroll
      for (int e = 0; e < 4; ++e) if (e < st) ra[e] += ra[e + st];
    lsum += xh_sum(ra[0]);

    // ---- P fragments: cvt_pk + permlane32_swap (T12) ----
    auto mkfrag = [&](int base) -> short8 {
      unsigned a0 = pk_bf16(s[base + 0], s[base + 1]);
      unsigned a1 = pk_bf16(s[base + 2], s[base + 3]);
      unsigned b0 = pk_bf16(s[base + 4], s[base + 5]);
      unsigned b1 = pk_bf16(s[base + 6], s[base + 7]);
      swap32(a0, b0);
      swap32(a1, b1);
      union { unsigned u[4]; short8 s8; } f;
      f.u[0] = a0; f.u[1] = a1; f.u[2] = b0; f.u[3] = b1;
      return f.s8;
    };
    short8 pf0 = mkfrag(0), pf1 = mkfrag(8);

    // ---- O^T += V^T · P^T ----
    __builtin_amdgcn_s_setprio(1);
    ot0 = __builtin_amdgcn_mfma_f32_32x32x16_bf16(cv[0], pf0, ot0, 0, 0, 0);
    ot0 = __builtin_amdgcn_mfma_f32_32x32x16_bf16(cv[1], pf1, ot0, 0, 0, 0);
    ot1 = __builtin_amdgcn_mfma_f32_32x32x16_bf16(cv[2], pf0, ot1, 0, 0, 0);
    ot1 = __builtin_amdgcn_mfma_f32_32x32x16_bf16(cv[3], pf1, ot1, 0, 0, 0);
    __builtin_amdgcn_s_setprio(0);
  };

  for (int t = 0; t < nt; t += 2) {
    body(kA, vA, kB, vB, t);
    if (t + 1 < nt) body(kB, vB, kA, vA, t + 1);
  }

  // ---- epilogue: Y (B,L,E) bf16, packed 8B stores ----
  float inv = 1.0f / lsum;
  unsigned short* Yr = Y + ((size_t)b * LL + qrow) * EE + h * DD;
  #pragma unroll
  for (int rg = 0; rg < 4; ++rg) {
    union { unsigned short s[4]; uint2 u; } o0, o1;
    #pragma unroll
    for (int e = 0; e < 4; ++e) {
      o0.s[e] = f32_bf16(ot0[rg * 4 + e] * inv);
      o1.s[e] = f32_bf16(ot1[rg * 4 + e] * inv);
    }
    *(uint2*)(Yr + rg * 8 + hi * 4) = o0.u;
    *(uint2*)(Yr + 32 + rg * 8 + hi * 4) = o1.u;
  }
}

// ---------------- launch ----------------
extern "C" void kernel_launch(void* const* d_in, const int* in_sizes, int n_in,
                              void* d_out, int out_size, void* d_ws, size_t ws_size,
                              hipStream_t stream) {
  const float* x    = (const float*)d_in[0];
  const float* mask = (const float*)d_in[1];
  const float* Wq   = (const float*)d_in[2];
  const float* Wk   = (const float*)d_in[3];
  const float* Wv   = (const float*)d_in[4];
  const float* Wo   = (const float*)d_in[5];
  const float* bo   = (const float*)d_in[6];
  float* out = (float*)d_out;

  char* ws = (char*)d_ws;
  unsigned short* xb  = (unsigned short*)(ws);
  unsigned short* wqb = (unsigned short*)(ws + ((size_t)8  << 20));
  unsigned short* wkb = (unsigned short*)(ws + ((size_t)10 << 20));
  unsigned short* wvb = (unsigned short*)(ws + ((size_t)12 << 20));
  unsigned short* wob = (unsigned short*)(ws + ((size_t)14 << 20));
  unsigned short* Qb  = (unsigned short*)(ws + ((size_t)16 << 20));
  unsigned short* Kb  = (unsigned short*)(ws + ((size_t)24 << 20));
  unsigned short* VTb = (unsigned short*)(ws + ((size_t)32 << 20));
  unsigned short* Yb  = (unsigned short*)(ws + ((size_t)40 << 20));

  cvt_all<<<8192, 256, 0, stream>>>(x, Wq, Wk, Wv, Wo, xb, wqb, wkb, wvb, wob);

  gemm128<0><<<dim3(EE / 128, MM / 128, 3), 256, 0, stream>>>(
      xb, wqb, wkb, wvb, mask, nullptr, Qb, Kb, VTb, nullptr);

  attn3<<<dim3(2048), 64, 0, stream>>>(Qb, Kb, VTb, Yb);

  gemm128<1><<<dim3(EE / 128, MM / 128, 1), 256, 0, stream>>>(
      Yb, wob, nullptr, nullptr, nullptr, bo, nullptr, nullptr, nullptr, out);
}

// Round 7
// 121.423 us; speedup vs baseline: 1.1429x; 1.1429x over previous
//
#include <hip/hip_runtime.h>
#include <cstdint>
#include <cstddef>
#include <math.h>

// B=2, L=2048, E=1024, H=16, D=64
#define BB 2
#define LL 2048
#define EE 1024
#define HH 16
#define DD 64
#define MM (BB*LL)

typedef short short8 __attribute__((ext_vector_type(8)));
typedef float f32x4 __attribute__((ext_vector_type(4)));
typedef float f32x16 __attribute__((ext_vector_type(16)));

#define GPTR __attribute__((address_space(1)))
#define LPTR __attribute__((address_space(3)))

__device__ __forceinline__ unsigned short f32_bf16(float f) {
  union { float f; unsigned u; } c; c.f = f;
  c.u += 0x7fffu + ((c.u >> 16) & 1u);
  return (unsigned short)(c.u >> 16);
}

__device__ __forceinline__ unsigned pk_bf16(float lo, float hi) {
  unsigned r;
  asm("v_cvt_pk_bf16_f32 %0, %1, %2" : "=v"(r) : "v"(lo), "v"(hi));
  return r;
}
// v_permlane32_swap_b32 vdst, vsrc — operands must be DISTINCT live values.
__device__ __forceinline__ void swap32(unsigned &a, unsigned &b) {
  asm("v_permlane32_swap_b32 %0, %1" : "+v"(a), "+v"(b));
}
// cross-half (lane vs lane^32) reduce via permlane32_swap (VALU-speed, no DS op)
__device__ __forceinline__ float xh_max(float v) {
  union { float f; unsigned u; } a, b;
  a.f = v;
  asm("v_mov_b32 %0, %1" : "=&v"(b.u) : "v"(a.u));
  asm("v_permlane32_swap_b32 %0, %1" : "+v"(a.u), "+v"(b.u));
  return fmaxf(a.f, b.f);
}
__device__ __forceinline__ float xh_sum(float v) {
  union { float f; unsigned u; } a, b;
  a.f = v;
  asm("v_mov_b32 %0, %1" : "=&v"(b.u) : "v"(a.u));
  asm("v_permlane32_swap_b32 %0, %1" : "+v"(a.u), "+v"(b.u));
  return a.f + b.f;
}
__device__ __forceinline__ f32x16 zero16() {
  f32x16 v;
  #pragma unroll
  for (int e = 0; e < 16; ++e) v[e] = 0.f;
  return v;
}

// ---------------- fp32 -> bf16 conversion (x + 4 weights fused) ----------------
__global__ void cvt_all(const float* __restrict__ x,  const float* __restrict__ wq,
                        const float* __restrict__ wk, const float* __restrict__ wv,
                        const float* __restrict__ wo,
                        unsigned short* __restrict__ xb,  unsigned short* __restrict__ wqb,
                        unsigned short* __restrict__ wkb, unsigned short* __restrict__ wvb,
                        unsigned short* __restrict__ wob)
{
  int i = (blockIdx.x * 256 + threadIdx.x) * 4;
  if (i >= MM * EE + 4 * EE * EE) return;
  const float* s; unsigned short* d; int off;
  if (i < MM * EE) { s = x; d = xb; off = i; }
  else {
    int k = i - MM * EE;
    int w = k >> 20;               // EE*EE = 1<<20
    off = k & (EE * EE - 1);
    s = (w == 0) ? wq : (w == 1) ? wk : (w == 2) ? wv : wo;
    d = (w == 0) ? wqb : (w == 1) ? wkb : (w == 2) ? wvb : wob;
  }
  float4 v = *(const float4*)(s + off);
  union { unsigned short s[4]; uint2 u; } o;
  o.s[0] = f32_bf16(v.x); o.s[1] = f32_bf16(v.y);
  o.s[2] = f32_bf16(v.z); o.s[3] = f32_bf16(v.w);
  *(uint2*)(d + off) = o.u;
}

// ---------------- 128x128 bf16 GEMM (NT: A MxK, W NxK) ----------------
// MODE 0: z=0: Q -> (B,H,L,D), *mask*(1/sqrt(D))*log2(e); z=1: K -> (B,H,L,D), *mask;
//         z=2: V^T -> kv-blocked (B,H)[L/32][D][32], *mask.
// MODE 1: out = A @ W0^T + bias, fp32 row-major.
template<int MODE>
__global__ __launch_bounds__(256, 2)
void gemm128(const unsigned short* __restrict__ A,
             const unsigned short* __restrict__ W0,
             const unsigned short* __restrict__ W1,
             const unsigned short* __restrict__ W2,
             const float* __restrict__ mask,
             const float* __restrict__ bias,
             unsigned short* __restrict__ O0,
             unsigned short* __restrict__ O1,
             unsigned short* __restrict__ O2,
             float* __restrict__ OF)
{
  constexpr int K = EE;
  const int tid = threadIdx.x;
  const int lane = tid & 63;
  const int wid = tid >> 6;
  const int g = lane >> 4, li = lane & 15;
  const int m0 = blockIdx.y * 128;
  const int n0 = blockIdx.x * 128;
  const int z = blockIdx.z;

  const unsigned short* Wp = W0;
  if (MODE == 0) Wp = (z == 0) ? W0 : ((z == 1) ? W1 : W2);

  __shared__ unsigned short As[128 * 64];
  __shared__ unsigned short Bs[128 * 64];

  f32x4 acc[4][4];
  f32x4 zero = {0.f, 0.f, 0.f, 0.f};
  #pragma unroll
  for (int i = 0; i < 4; ++i)
    #pragma unroll
    for (int j = 0; j < 4; ++j) acc[i][j] = zero;

  const int wm = (wid >> 1) * 64;
  const int wn = (wid & 1) * 64;

  for (int kt = 0; kt < K; kt += 64) {
    #pragma unroll
    for (int j = 0; j < 4; ++j) {
      int c = j * 256 + tid;
      int row = c >> 3;
      int lcol = ((c & 7) * 16) ^ ((row & 7) << 4);
      __builtin_amdgcn_global_load_lds(
        (const GPTR void*)((const char*)(A + (size_t)(m0 + row) * K + kt) + lcol),
        (LPTR void*)((char*)As + c * 16), 16, 0, 0);
      __builtin_amdgcn_global_load_lds(
        (const GPTR void*)((const char*)(Wp + (size_t)(n0 + row) * K + kt) + lcol),
        (LPTR void*)((char*)Bs + c * 16), 16, 0, 0);
    }
    __syncthreads();

    #pragma unroll
    for (int kk = 0; kk < 2; ++kk) {
      short8 a[4], b[4];
      const int colb = (kk * 32 + g * 8) * 2;
      #pragma unroll
      for (int i = 0; i < 4; ++i) {
        int ar = wm + i * 16 + li;
        a[i] = *(const short8*)((const char*)As + ar * 128 + (colb ^ ((ar & 7) << 4)));
        int br = wn + i * 16 + li;
        b[i] = *(const short8*)((const char*)Bs + br * 128 + (colb ^ ((br & 7) << 4)));
      }
      #pragma unroll
      for (int i = 0; i < 4; ++i)
        #pragma unroll
        for (int j = 0; j < 4; ++j)
          acc[i][j] = __builtin_amdgcn_mfma_f32_16x16x32_bf16(a[i], b[j], acc[i][j], 0, 0, 0);
    }
    __syncthreads();
  }

  // epilogue. C/D layout: col = li, row = g*4 + r
  if (MODE == 0) {
    if (z == 2) {
      // V^T kv-blocked: per head [L/32][D=64][32], each 32-kv tile = 4KB contiguous
      #pragma unroll
      for (int i = 0; i < 4; ++i) {
        int mbase = m0 + wm + i * 16 + g * 4;
        int bb2 = mbase >> 11;
        int l0  = mbase & (LL - 1);
        float mk[4];
        #pragma unroll
        for (int r = 0; r < 4; ++r) mk[r] = mask[mbase + r];
        #pragma unroll
        for (int j = 0; j < 4; ++j) {
          int n = n0 + wn + j * 16 + li;
          int h2 = n >> 6, dd2 = n & 63;
          union { unsigned short s[4]; uint2 u; } o;
          #pragma unroll
          for (int r = 0; r < 4; ++r) o.s[r] = f32_bf16(acc[i][j][r] * mk[r]);
          size_t off = (size_t)(bb2 * HH + h2) * (LL * DD)
                     + (size_t)(l0 >> 5) * (DD * 32) + dd2 * 32 + (l0 & 31);
          *(uint2*)(O2 + off) = o.u;
        }
      }
    } else {
      unsigned short* Op = (z == 0) ? O0 : O1;
      // z==0: 1/sqrt(64) * log2(e) folded into Q (softmax runs in exp2 domain)
      const float sc = (z == 0) ? 0.125f * 1.44269504088896f : 1.0f;
      #pragma unroll
      for (int i = 0; i < 4; ++i) {
        #pragma unroll
        for (int r = 0; r < 4; ++r) {
          int m = m0 + wm + i * 16 + g * 4 + r;
          float mk = mask[m] * sc;
          int bb = m >> 11;
          int l  = m & (LL - 1);
          #pragma unroll
          for (int j = 0; j < 4; ++j) {
            int n = n0 + wn + j * 16 + li;
            int h = n >> 6, d = n & 63;
            size_t off = (((size_t)(bb * HH + h)) * LL + l) * DD + d;
            Op[off] = f32_bf16(acc[i][j][r] * mk);
          }
        }
      }
    }
  } else {
    #pragma unroll
    for (int i = 0; i < 4; ++i) {
      #pragma unroll
      for (int j = 0; j < 4; ++j) {
        int n = n0 + wn + j * 16 + li;
        float bv = bias[n];
        #pragma unroll
        for (int r = 0; r < 4; ++r) {
          int m = m0 + wm + i * 16 + g * 4 + r;
          OF[(size_t)m * EE + n] = acc[i][j][r] + bv;
        }
      }
    }
  }
}

// ---------------- causal flash attention: 2-wave kv-split, no in-loop barriers ----
// Q (B,H,L,D) *mask*(1/sqrt(D))*log2e; K (B,H,L,D) *mask; VT kv-blocked [L/32][64][32] *mask.
// Block = 2 waves, both own the SAME 32 q-rows; wave w handles kv tiles t≡w (mod 2).
// Private (m,lsum,O) per wave; one LDS merge + single barrier at the end.
// K tile (32 rows x 128B) and V^T tile (4KB block) are both CONTIGUOUS -> clean L2.
__global__ __launch_bounds__(128)
void attn4(const unsigned short* __restrict__ Q,
           const unsigned short* __restrict__ K,
           const unsigned short* __restrict__ VT,
           unsigned short* __restrict__ Y)
{
  const int tid = threadIdx.x, lane = tid & 63, w = tid >> 6;
  const int l31 = lane & 31, hi = lane >> 5;

  const int id = blockIdx.x;
  const int lo = id & 7;                    // XCD
  const int r_ = id >> 3;
  const int bh = (r_ & 3) * 8 + lo;         // 4 heads per XCD (KV 2MB <= 4MB L2)
  const int qt = 63 - (r_ >> 2);            // heavy q-tiles first
  const int q0 = qt * 32;
  const int b = bh >> 4, h = bh & (HH - 1);
  const size_t kbase = (size_t)bh * LL * DD;

  const unsigned short* Kg  = K + kbase;
  const unsigned short* VTg = VT + kbase;   // kv-blocked within head

  const int qrow = q0 + l31;
  const int nt = qt + 1;                    // kv tiles of 32

  short8 qf[4];
  {
    const unsigned short* Qr = Q + kbase + (size_t)qrow * DD + hi * 8;
    #pragma unroll
    for (int kc = 0; kc < 4; ++kc) qf[kc] = *(const short8*)(Qr + kc * 16);
  }

  f32x16 ot0 = zero16(), ot1 = zero16();
  float m = -INFINITY, lsum = 0.f;

  short8 kA[4], vA[4], kB[4], vB[4];

  // load tile t into (k,v) register buffers; K tile contiguous, V^T tile = one 4KB block
  auto loadtile = [&](short8 (&kk)[4], short8 (&vv)[4], int t2) {
    const int kv0 = t2 << 5;
    const unsigned short* Kp = Kg + ((size_t)(kv0 + l31) << 6) + hi * 8;
    #pragma unroll
    for (int kc = 0; kc < 4; ++kc) kk[kc] = *(const short8*)(Kp + kc * 16);
    const unsigned short* Vp = VTg + (size_t)(kv0 >> 5) * (DD * 32) + l31 * 32 + hi * 8;
    vv[0] = *(const short8*)(Vp);
    vv[1] = *(const short8*)(Vp + 16);
    vv[2] = *(const short8*)(Vp + 32 * 32);
    vv[3] = *(const short8*)(Vp + 32 * 32 + 16);
  };

  // prologue: wave w's first tile (t = w). Memory always in-bounds (kv < L).
  loadtile(kA, vA, w);

  auto body = [&](short8 (&ck)[4], short8 (&cv)[4],
                  short8 (&nk)[4], short8 (&nv)[4], int t) {
    // prefetch tile t+2 (this wave's next) into the other buffers
    if (t + 2 < nt) loadtile(nk, nv, t + 2);

    const int kv0 = t << 5;

    // ---- S^T = K · Q^T (log2 units) ----
    f32x16 s = zero16();
    __builtin_amdgcn_s_setprio(1);
    #pragma unroll
    for (int kc = 0; kc < 4; ++kc)
      s = __builtin_amdgcn_mfma_f32_32x32x16_bf16(ck[kc], qf[kc], s, 0, 0, 0);
    __builtin_amdgcn_s_setprio(0);

    // ---- causal mask: diagonal tile only (kv0 == q0) ----
    if (t == nt - 1) {
      #pragma unroll
      for (int i = 0; i < 16; ++i) {
        int kvr = (i & 3) + 8 * (i >> 2) + 4 * hi;   // kv - kv0
        if (kvr > l31) s[i] = -INFINITY;
      }
    }

    // ---- online softmax (exp2 domain), lane-local + permlane cross-half ----
    float red[8];
    #pragma unroll
    for (int e = 0; e < 8; ++e) red[e] = fmaxf(s[e], s[e + 8]);
    #pragma unroll
    for (int st = 4; st >= 1; st >>= 1)
      #pragma unroll
      for (int e = 0; e < 4; ++e) if (e < st) red[e] = fmaxf(red[e], red[e + st]);
    float mv = xh_max(red[0]);

    if (!__all(mv <= m + 8.0f)) {            // T13 defer-max (P bounded by 2^8)
      float mnew = fmaxf(m, mv);
      float al = exp2f(m - mnew);
      m = mnew;
      lsum *= al;
      #pragma unroll
      for (int e = 0; e < 16; ++e) { ot0[e] *= al; ot1[e] *= al; }
    }

    float ra[8];
    #pragma unroll
    for (int e = 0; e < 16; ++e) s[e] = exp2f(s[e] - m);
    #pragma unroll
    for (int e = 0; e < 8; ++e) ra[e] = s[e] + s[e + 8];
    #pragma unroll
    for (int st = 4; st >= 1; st >>= 1)
      #pragma unroll
      for (int e = 0; e < 4; ++e) if (e < st) ra[e] += ra[e + st];
    lsum += xh_sum(ra[0]);

    // ---- P fragments: cvt_pk + permlane32_swap (T12) ----
    auto mkfrag = [&](int base) -> short8 {
      unsigned a0 = pk_bf16(s[base + 0], s[base + 1]);
      unsigned a1 = pk_bf16(s[base + 2], s[base + 3]);
      unsigned b0 = pk_bf16(s[base + 4], s[base + 5]);
      unsigned b1 = pk_bf16(s[base + 6], s[base + 7]);
      swap32(a0, b0);
      swap32(a1, b1);
      union { unsigned u[4]; short8 s8; } f;
      f.u[0] = a0; f.u[1] = a1; f.u[2] = b0; f.u[3] = b1;
      return f.s8;
    };
    short8 pf0 = mkfrag(0), pf1 = mkfrag(8);

    // ---- O^T += V^T · P^T ----
    __builtin_amdgcn_s_setprio(1);
    ot0 = __builtin_amdgcn_mfma_f32_32x32x16_bf16(cv[0], pf0, ot0, 0, 0, 0);
    ot0 = __builtin_amdgcn_mfma_f32_32x32x16_bf16(cv[1], pf1, ot0, 0, 0, 0);
    ot1 = __builtin_amdgcn_mfma_f32_32x32x16_bf16(cv[2], pf0, ot1, 0, 0, 0);
    ot1 = __builtin_amdgcn_mfma_f32_32x32x16_bf16(cv[3], pf1, ot1, 0, 0, 0);
    __builtin_amdgcn_s_setprio(0);
  };

  // wave w processes tiles w, w+2, w+4, ... (private online softmax state)
  for (int t = w; t < nt; t += 4) {
    body(kA, vA, kB, vB, t);
    if (t + 2 < nt) body(kB, vB, kA, vA, t + 2);
  }

  // ---- merge the two waves' partials via LDS (single barrier) ----
  __shared__ float mg[64][34];   // wave1's state: [lane][m,lsum,ot0[16],ot1[16]]
  if (w == 1) {
    mg[lane][0] = m; mg[lane][1] = lsum;
    #pragma unroll
    for (int e = 0; e < 16; ++e) { mg[lane][2 + e] = ot0[e]; mg[lane][18 + e] = ot1[e]; }
  }
  __syncthreads();
  if (w == 0) {
    float m1 = mg[lane][0], l1 = mg[lane][1];
    float M = fmaxf(m, m1);
    float a0 = exp2f(m - M), a1 = exp2f(m1 - M);
    float Lt = lsum * a0 + l1 * a1;
    float inv = 1.0f / Lt;
    unsigned short* Yr = Y + ((size_t)b * LL + qrow) * EE + h * DD;
    #pragma unroll
    for (int rg = 0; rg < 4; ++rg) {
      union { unsigned short s[4]; uint2 u; } o0, o1;
      #pragma unroll
      for (int e = 0; e < 4; ++e) {
        int i = rg * 4 + e;
        o0.s[e] = f32_bf16((ot0[i] * a0 + mg[lane][2 + i]  * a1) * inv);
        o1.s[e] = f32_bf16((ot1[i] * a0 + mg[lane][18 + i] * a1) * inv);
      }
      *(uint2*)(Yr + rg * 8 + hi * 4) = o0.u;
      *(uint2*)(Yr + 32 + rg * 8 + hi * 4) = o1.u;
    }
  }
}

// ---------------- launch ----------------
extern "C" void kernel_launch(void* const* d_in, const int* in_sizes, int n_in,
                              void* d_out, int out_size, void* d_ws, size_t ws_size,
                              hipStream_t stream) {
  const float* x    = (const float*)d_in[0];
  const float* mask = (const float*)d_in[1];
  const float* Wq   = (const float*)d_in[2];
  const float* Wk   = (const float*)d_in[3];
  const float* Wv   = (const float*)d_in[4];
  const float* Wo   = (const float*)d_in[5];
  const float* bo   = (const float*)d_in[6];
  float* out = (float*)d_out;

  char* ws = (char*)d_ws;
  unsigned short* xb  = (unsigned short*)(ws);
  unsigned short* wqb = (unsigned short*)(ws + ((size_t)8  << 20));
  unsigned short* wkb = (unsigned short*)(ws + ((size_t)10 << 20));
  unsigned short* wvb = (unsigned short*)(ws + ((size_t)12 << 20));
  unsigned short* wob = (unsigned short*)(ws + ((size_t)14 << 20));
  unsigned short* Qb  = (unsigned short*)(ws + ((size_t)16 << 20));
  unsigned short* Kb  = (unsigned short*)(ws + ((size_t)24 << 20));
  unsigned short* VTb = (unsigned short*)(ws + ((size_t)32 << 20));
  unsigned short* Yb  = (unsigned short*)(ws + ((size_t)40 << 20));

  cvt_all<<<8192, 256, 0, stream>>>(x, Wq, Wk, Wv, Wo, xb, wqb, wkb, wvb, wob);

  gemm128<0><<<dim3(EE / 128, MM / 128, 3), 256, 0, stream>>>(
      xb, wqb, wkb, wvb, mask, nullptr, Qb, Kb, VTb, nullptr);

  attn4<<<dim3(2048), 128, 0, stream>>>(Qb, Kb, VTb, Yb);

  gemm128<1><<<dim3(EE / 128, MM / 128, 1), 256, 0, stream>>>(
      Yb, wob, nullptr, nullptr, nullptr, bo, nullptr, nullptr, nullptr, out);
}